// Round 8
// baseline (2287.233 us; speedup 1.0000x reference)
//
#include <hip/hip_runtime.h>

typedef unsigned short u16;
typedef unsigned int   u32;
typedef __bf16 bf16x8 __attribute__((ext_vector_type(8)));
typedef float  f32x4  __attribute__((ext_vector_type(4)));
typedef u16    u16x4  __attribute__((ext_vector_type(4)));
typedef u32    u32x4  __attribute__((ext_vector_type(4)));

#define NTOK 21760
#define TTOK 43520   // BS * NTOK
#define DMODEL 256

__device__ __forceinline__ u16 f2bf(float f){
  u32 u = __builtin_bit_cast(u32, f);
  u32 r = u + 0x7fffu + ((u >> 16) & 1u);
  return (u16)(r >> 16);
}
__device__ __forceinline__ float bf2f(u16 h){
  u32 u = ((u32)h) << 16;
  return __builtin_bit_cast(float, u);
}
__device__ __forceinline__ float lo16(u32 u){ return __builtin_bit_cast(float, u << 16); }
__device__ __forceinline__ float hi16(u32 u){ return __builtin_bit_cast(float, u & 0xffff0000u); }

__device__ __forceinline__ void gld16(const u16* g, u16* l){
  __builtin_amdgcn_global_load_lds((const __attribute__((address_space(1))) void*)g,
                                   (__attribute__((address_space(3))) void*)l, 16, 0, 0);
}

// ---------------- weight prep ----------------
__global__ void cvt_plain(const float* __restrict__ s, u16* __restrict__ d, int n){
  int i = blockIdx.x * 256 + threadIdx.x;
  if (i < n) d[i] = f2bf(s[i]);
}
__global__ void build_oa_w(const float* __restrict__ Wo, const float* __restrict__ Wa, u16* __restrict__ dst){
  int i = blockIdx.x * 256 + threadIdx.x;
  if (i >= 6*384*256) return;
  int l = i / (384*256); int rem = i % (384*256); int r = rem >> 8; int c = rem & 255;
  float v = (r < 256) ? Wo[((size_t)l*256 + r)*256 + c] : Wa[((size_t)l*128 + (r-256))*256 + c];
  dst[i] = f2bf(v);
}
__global__ void build_oa_b(const float* __restrict__ bo, const float* __restrict__ ba, float* __restrict__ dst){
  int i = blockIdx.x * 256 + threadIdx.x;
  if (i >= 6*384) return;
  int l = i / 384; int r = i % 384;
  dst[i] = (r < 256) ? bo[l*256 + r] : ba[l*128 + (r-256)];
}
__global__ void build_w13(const float* __restrict__ W1, const float* __restrict__ W3, u16* __restrict__ dst){
  int i = blockIdx.x * 256 + threadIdx.x;
  if (i >= 6*2048*256) return;
  int l = i / (2048*256); int rem = i % (2048*256); int r = rem >> 8; int c = rem & 255;
  int f = r >> 1; int s = r & 1;
  const float* W = s ? W3 : W1;
  dst[i] = f2bf(W[((size_t)l*1024 + f)*256 + c]);
}
__global__ void build_b13(const float* __restrict__ b1, const float* __restrict__ b3, float* __restrict__ dst){
  int i = blockIdx.x * 256 + threadIdx.x;
  if (i >= 6*2048) return;
  int l = i / 2048; int r = i % 2048;
  dst[i] = (r & 1) ? b3[l*1024 + (r>>1)] : b1[l*1024 + (r>>1)];
}

// ---------------- input prep: q init (fp32 copy w/ transpose) + posf (bf16) ----------------
__global__ __launch_bounds__(256)
void prep_level(const float* __restrict__ src, const float* __restrict__ pos,
                const float* __restrict__ lemb, float* __restrict__ q,
                u16* __restrict__ posf, int HW, int nstart){
  __shared__ float tS[32][65];
  __shared__ float tP[32][65];
  int b  = blockIdx.z;
  int d0 = blockIdx.y * 32;
  int n0 = blockIdx.x * 64;
  int tx = threadIdx.x & 63, ty = threadIdx.x >> 6;
  #pragma unroll
  for (int i = 0; i < 8; ++i){
    int d = i*4 + ty;
    size_t gi = ((size_t)b*DMODEL + d0 + d) * HW + n0 + tx;
    tS[d][tx] = src[gi];
    tP[d][tx] = pos[gi];
  }
  __syncthreads();
  int dc = threadIdx.x & 31, nl0 = threadIdx.x >> 5;
  float le = lemb[d0 + dc];
  #pragma unroll
  for (int ii = 0; ii < 8; ++ii){
    int nl = nl0 + ii*8;
    size_t oi = ((size_t)b*NTOK + nstart + n0 + nl) * DMODEL + d0 + dc;
    q[oi]    = tS[dc][nl];
    posf[oi] = f2bf(tP[dc][nl] + le);
  }
}

__global__ void tail_writer(float* __restrict__ out){
  const float vals[12] = {128.f,128.f,64.f,64.f,32.f,32.f,16.f,16.f,
                          0.f,16384.f,20480.f,21504.f};
  int t = threadIdx.x;
  if (t < 12) out[(size_t)TTOK*DMODEL + t] = vals[t];
}

// ---------------- rmsnorm (+ optional qin = n + posf) ----------------
__global__ __launch_bounds__(256)
void rmsnorm_k(const float* __restrict__ q, const float* __restrict__ g,
               const u16* __restrict__ posf, u16* __restrict__ nout,
               u16* __restrict__ qinout){
  int tok  = blockIdx.x*4 + (threadIdx.x >> 6);
  int lane = threadIdx.x & 63;
  const f32x4* qr = (const f32x4*)(q + (size_t)tok*DMODEL);
  f32x4 v = qr[lane];
  float ss = v[0]*v[0] + v[1]*v[1] + v[2]*v[2] + v[3]*v[3];
  #pragma unroll
  for (int o = 32; o > 0; o >>= 1) ss += __shfl_xor(ss, o);
  float sc = rsqrtf(ss * (1.0f/256.0f) + 1e-6f);
  f32x4 gv = ((const f32x4*)g)[lane];
  float nf[4]; u16x4 nv;
  #pragma unroll
  for (int r = 0; r < 4; ++r){ nf[r] = v[r]*sc*gv[r]; nv[r] = f2bf(nf[r]); }
  ((u16x4*)(nout + (size_t)tok*DMODEL))[lane] = nv;
  if (qinout){
    u16x4 pf = ((const u16x4*)(posf + (size_t)tok*DMODEL))[lane];
    u16x4 qv;
    #pragma unroll
    for (int r = 0; r < 4; ++r) qv[r] = f2bf(nf[r] + bf2f(pf[r]));
    ((u16x4*)(qinout + (size_t)tok*DMODEL))[lane] = qv;
  }
}

// ---------------- GEMM: C[m,n] = sum_k A[m,k]*B[n,k]  (A,B bf16, NT) ----------------
// XCD-swizzled (bijective, m204). 3-buffer LDS pipeline with counted vmcnt
// (T4/HK pattern): raw s_barrier + s_waitcnt vmcnt(4) keeps the next-next
// tile's 4 global_load_lds in flight ACROSS the barrier (no vmcnt(0) drain),
// hiding staging latency -- the short-K (8-step) loops were drain-bound.
// EPI 0: out bf16 = acc + bias          (ldo = N of this gemm)
// EPI 1: swiglu:   out bf16 h[m, col>>1] = silu(h1)*h3, cols interleaved (ldo = N/2)
// EPI 2: residual: out f32 += ls[col] * (acc + bias)   (ldo = N)
// EPI 3: value head-planes: out bf16 [(b*8+head)][tok][32], head=col>>5
// EPI 4: oa48 rows: out bf16 [(b*8+head)][tok][48]; col<256 -> offs[col&31],
//        col>=256 -> logits 32+(c&15), head=c>>4
template<int EPI>
__global__ __launch_bounds__(256)
void gemm_bt(const u16* __restrict__ A, const u16* __restrict__ B,
             const float* __restrict__ bias, void* __restrict__ outp,
             const float* __restrict__ ls, int K, int ldo){
  __shared__ u16 lds[3][2][4096];
  const int tid = threadIdx.x, lane = tid & 63, w = tid >> 6;
  const int wm = w >> 1, wn = w & 1;

  // bijective XCD swizzle
  const int gx = gridDim.x;
  const int nwg = gx * gridDim.y;
  const int id  = blockIdx.y * gx + blockIdx.x;
  const int q8 = nwg >> 3, r8 = nwg & 7;
  const int xcd = id & 7, pos = id >> 3;
  const int nid = (xcd < r8 ? xcd * (q8 + 1) : r8 * (q8 + 1) + (xcd - r8) * q8) + pos;
  const int bn = (nid % gx) * 128, bm = (nid / gx) * 128;

  const int fr = lane & 15, ks = lane >> 4;

  const u16* gA = A + (size_t)(bm + w*32 + (lane >> 2)) * K + (lane & 3) * 8;
  const u16* gB = B + (size_t)(bn + w*32 + (lane >> 2)) * K + (lane & 3) * 8;
  const size_t rstep = (size_t)16 * K;

  f32x4 acc[4][4];
  #pragma unroll
  for (int m = 0; m < 4; ++m)
    #pragma unroll
    for (int n = 0; n < 4; ++n) acc[m][n] = (f32x4){0.f,0.f,0.f,0.f};

  const int aoff = (wm*64 + fr)*32 + ks*8;
  const int boff = (wn*64 + fr)*32 + ks*8;

  auto STAGE = [&](int buf, int t){
    const int k0 = t * 32;
    gld16(gA + k0,         &lds[buf][0][w*1024]);
    gld16(gA + k0 + rstep, &lds[buf][0][w*1024 + 512]);
    gld16(gB + k0,         &lds[buf][1][w*1024]);
    gld16(gB + k0 + rstep, &lds[buf][1][w*1024 + 512]);
  };

  const int nk = K >> 5;     // all call sites have nk >= 8
  STAGE(0, 0);
  STAGE(1, 1);
  // buf0's 4 loads complete (4 newest, for buf1, stay in flight)
  asm volatile("s_waitcnt vmcnt(4)" ::: "memory");
  __builtin_amdgcn_s_barrier();

  for (int t = 0; t < nk; ++t){
    const int cb = t % 3;
    if (t + 2 < nk) STAGE((t + 2) % 3, t + 2);
    bf16x8 af[4], bb[4];
    #pragma unroll
    for (int m = 0; m < 4; ++m) af[m] = *(const bf16x8*)&lds[cb][0][aoff + m*512];
    #pragma unroll
    for (int n = 0; n < 4; ++n) bb[n] = *(const bf16x8*)&lds[cb][1][boff + n*512];
    #pragma unroll
    for (int m = 0; m < 4; ++m)
      #pragma unroll
      for (int n = 0; n < 4; ++n)
        acc[m][n] = __builtin_amdgcn_mfma_f32_16x16x32_bf16(af[m], bb[n], acc[m][n], 0, 0, 0);
    // next buffer ready; deepest prefetch (4 loads) stays outstanding
    if (t + 2 < nk) asm volatile("s_waitcnt vmcnt(4)" ::: "memory");
    else            asm volatile("s_waitcnt vmcnt(0)" ::: "memory");
    __builtin_amdgcn_s_barrier();
  }

  const int colb = bn + wn*64 + fr;
  const int rowb = bm + wm*64 + ks*4;

  if (EPI == 0){
    u16* o = (u16*)outp;
    #pragma unroll
    for (int n = 0; n < 4; ++n){
      int col = colb + n*16; float bv = bias[col];
      #pragma unroll
      for (int m = 0; m < 4; ++m){
        int row = rowb + m*16;
        #pragma unroll
        for (int r = 0; r < 4; ++r)
          o[(size_t)(row + r)*ldo + col] = f2bf(acc[m][n][r] + bv);
      }
    }
  } else if (EPI == 1){
    u16* o = (u16*)outp;
    #pragma unroll
    for (int n = 0; n < 4; ++n){
      int col = colb + n*16; float bv = bias[col];
      int f = col >> 1; bool even = ((col & 1) == 0);
      #pragma unroll
      for (int m = 0; m < 4; ++m){
        int row = rowb + m*16;
        #pragma unroll
        for (int r = 0; r < 4; ++r){
          float v = acc[m][n][r] + bv;
          float other = __shfl_xor(v, 1);
          if (even){
            float res = (v / (1.0f + __expf(-v))) * other;   // silu(h1)*h3
            o[(size_t)(row + r)*ldo + f] = f2bf(res);
          }
        }
      }
    }
  } else if (EPI == 2){
    float* o = (float*)outp;
    #pragma unroll
    for (int n = 0; n < 4; ++n){
      int col = colb + n*16; float bv = bias[col]; float lv = ls[col];
      #pragma unroll
      for (int m = 0; m < 4; ++m){
        int row = rowb + m*16;
        #pragma unroll
        for (int r = 0; r < 4; ++r){
          size_t ix = (size_t)(row + r)*ldo + col;
          o[ix] += lv * (acc[m][n][r] + bv);
        }
      }
    }
  } else if (EPI == 3){
    // value head-planes
    u16* o = (u16*)outp;
    #pragma unroll
    for (int n = 0; n < 4; ++n){
      int col = colb + n*16; float bv = bias[col];
      int head = col >> 5, ch = col & 31;
      #pragma unroll
      for (int m = 0; m < 4; ++m){
        int row = rowb + m*16;
        #pragma unroll
        for (int r = 0; r < 4; ++r){
          int rw = row + r;
          int bb2 = rw >= NTOK ? 1 : 0;
          int tok = rw - bb2 * NTOK;
          o[((size_t)(bb2*8 + head)*NTOK + tok)*32 + ch] = f2bf(acc[m][n][r] + bv);
        }
      }
    }
  } else {
    // EPI 4: oa48 rows
    u16* o = (u16*)outp;
    #pragma unroll
    for (int n = 0; n < 4; ++n){
      int col = colb + n*16; float bv = bias[col];
      int head, within;
      if (col < 256){ head = col >> 5; within = col & 31; }
      else { int c = col - 256; head = c >> 4; within = 32 + (c & 15); }
      #pragma unroll
      for (int m = 0; m < 4; ++m){
        int row = rowb + m*16;
        #pragma unroll
        for (int r = 0; r < 4; ++r){
          int rw = row + r;
          int bb2 = rw >= NTOK ? 1 : 0;
          int tok = rw - bb2 * NTOK;
          o[((size_t)(bb2*8 + head)*NTOK + tok)*48 + within] = f2bf(acc[m][n][r] + bv);
        }
      }
    }
  }
}

// ---------------- deformable sampler ----------------
// Coalescing-first layout: wave = 32 CONSECUTIVE q (lanes 0-31 / 32-63 are the
// two level-halves of the same 32 q) for ONE (b,head). value is head-planed
// [(b*8+h)][tok][32]; oa packed [(b*8+h)][q][48]. Halves combine via
// shfl_xor(32). XCD chunking: each XCD owns 2 head-planes (~3MB, L2-fits).
__global__ __launch_bounds__(256)
void sampler_k(const u16* __restrict__ oa48, const u16* __restrict__ valpl,
               u16* __restrict__ samp){
  // 2720 blocks = 8 * 340; nid = bh*170 + qblock
  int nid = (blockIdx.x & 7) * 340 + (blockIdx.x >> 3);
  int bh = nid / 170, qb = nid % 170;
  int lane = threadIdx.x & 63, wv = threadIdx.x >> 6;
  int half = lane >> 5;
  int q = qb * 128 + wv * 32 + (lane & 31);

  int st, lw, sh;
  if (q < 16384){ st = 0;     lw = 128; sh = 7; }
  else if (q < 20480){ st = 16384; lw = 64; sh = 6; }
  else if (q < 21504){ st = 20480; lw = 32; sh = 5; }
  else { st = 21504; lw = 16; sh = 4; }
  int loc = q - st;
  int j = loc & (lw - 1), i = loc >> sh;
  float invW = 1.0f / (float)lw;
  float rx = (j + 0.5f) * invW, ry = (i + 0.5f) * invW;

  const u16* oq = oa48 + ((size_t)bh * NTOK + q) * 48;
  // softmax: each half exponentiates its own 8 logits; combine via shfl_xor(32)
  float lg[8];
  const u32* lg32 = (const u32*)(oq + 32) + half * 4;
  #pragma unroll
  for (int p = 0; p < 4; ++p){ u32 wd = lg32[p]; lg[2*p] = lo16(wd); lg[2*p+1] = hi16(wd); }
  float mx = -1e30f;
  #pragma unroll
  for (int p = 0; p < 8; ++p) mx = fmaxf(mx, lg[p]);
  mx = fmaxf(mx, __shfl_xor(mx, 32));
  float ssum = 0.f;
  #pragma unroll
  for (int p = 0; p < 8; ++p){ lg[p] = __expf(lg[p] - mx); ssum += lg[p]; }
  ssum += __shfl_xor(ssum, 32);
  float inv = 1.0f / ssum;

  float acc[32];
  #pragma unroll
  for (int d = 0; d < 32; ++d) acc[d] = 0.f;

  const u32* op32 = (const u32*)oq + half * 8;
  const u16* plane = valpl + (size_t)bh * NTOK * 32;
  #pragma unroll
  for (int il = 0; il < 2; ++il){
    const int Wl    = half ? (il ? 16 : 32)    : (il ? 64 : 128);
    const int start = half ? (il ? 21504 : 20480) : (il ? 16384 : 0);
    #pragma unroll
    for (int p = 0; p < 4; ++p){
      u32 wd = op32[il*4 + p];
      float x = rx * Wl + lo16(wd) - 0.5f;
      float y = ry * Wl + hi16(wd) - 0.5f;
      float x0f = floorf(x), y0f = floorf(y);
      int x0 = (int)x0f, y0 = (int)y0f;
      float fx = x - x0f, fy = y - y0f;
      float wp = lg[il*4 + p];
      #pragma unroll
      for (int c = 0; c < 4; ++c){
        int xi = x0 + (c & 1), yi = y0 + (c >> 1);
        float wc = ((c & 1) ? fx : 1.f - fx) * ((c >> 1) ? fy : 1.f - fy) * wp;
        if (xi >= 0 && xi < Wl && yi >= 0 && yi < Wl && wc != 0.f){
          const u32x4* vp = (const u32x4*)(plane + (size_t)(start + yi*Wl + xi) * 32);
          #pragma unroll
          for (int u4 = 0; u4 < 4; ++u4){
            u32x4 vv = vp[u4];
            #pragma unroll
            for (int jj = 0; jj < 4; ++jj){
              acc[8*u4 + 2*jj]     += wc * lo16(vv[jj]);
              acc[8*u4 + 2*jj + 1] += wc * hi16(vv[jj]);
            }
          }
        }
      }
    }
  }

  // combine halves: after this, both lanes hold the full 32-channel sum
  #pragma unroll
  for (int d = 0; d < 32; ++d) acc[d] += __shfl_xor(acc[d], 32);

  // lane writes its half's 16 channels
  u16* out = samp + ((size_t)(bh >> 3) * NTOK + q) * DMODEL + (bh & 7) * 32 + half * 16;
  #pragma unroll
  for (int d = 0; d < 16; d += 4){
    u16x4 o4;
    #pragma unroll
    for (int r = 0; r < 4; ++r) o4[r] = f2bf(acc[half*16 + d + r] * inv);
    *(u16x4*)(out + d) = o4;
  }
}

// ---------------- host ----------------
extern "C" void kernel_launch(void* const* d_in, const int* in_sizes, int n_in,
                              void* d_out, int out_size, void* d_ws, size_t ws_size,
                              hipStream_t stream){
  const float* src[4] = {(const float*)d_in[0], (const float*)d_in[2],
                         (const float*)d_in[4], (const float*)d_in[6]};
  const float* pos[4] = {(const float*)d_in[1], (const float*)d_in[3],
                         (const float*)d_in[5], (const float*)d_in[7]};
  const float* le     = (const float*)d_in[8];
  const float* W_off  = (const float*)d_in[9];  const float* b_off  = (const float*)d_in[10];
  const float* W_attn = (const float*)d_in[11]; const float* b_attn = (const float*)d_in[12];
  const float* W_val  = (const float*)d_in[13]; const float* b_val  = (const float*)d_in[14];
  const float* W_out  = (const float*)d_in[15]; const float* b_out  = (const float*)d_in[16];
  const float* g_na   = (const float*)d_in[17]; const float* g_nf   = (const float*)d_in[18];
  const float* ls_a   = (const float*)d_in[19]; const float* ls_f   = (const float*)d_in[20];
  const float* W1     = (const float*)d_in[21]; const float* b1     = (const float*)d_in[22];
  const float* W3     = (const float*)d_in[23]; const float* b3     = (const float*)d_in[24];
  const float* W2     = (const float*)d_in[25]; const float* b2     = (const float*)d_in[26];

  char* ws = (char*)d_ws;
  // ws layout (bytes)
  u16*   wv   = (u16*)  (ws + 0);          // 6*65536 bf16
  u16*   wpj  = (u16*)  (ws + 786432);     // W_out, 6*65536
  u16*   w2b  = (u16*)  (ws + 1572864);    // 6*262144
  u16*   woa  = (u16*)  (ws + 4718592);    // 6*384*256
  float* boa  = (float*)(ws + 5898240);    // 6*384
  u16*   w13  = (u16*)  (ws + 5907456);    // 6*2048*256
  float* bi13 = (float*)(ws + 12198912);   // 6*2048
  u16*   posfb= (u16*)  (ws + 12248064);   // 11141120 bf16
  u16*   nb   = (u16*)  (ws + 34530304);   // 11141120 bf16
  u16*   qinb = (u16*)  (ws + 56812544);   // 11141120 bf16
  u16*   valb = (u16*)  (ws + 79094784);   // 11141120 bf16 (head-planed)
  u16*   oab  = (u16*)  (ws + 101377024);  // 16*21760*48 bf16 (oa48)
  u16*   sampb= (u16*)  (ws + 134800384);  // 11141120 bf16
  u16*   hb   = qinb;                      // FFN h aliases qin (dead by then); 89 MB
  float* qf   = (float*)d_out;

  // weight prep
  cvt_plain<<<(393216+255)/256, 256, 0, stream>>>(W_val, wv, 393216);
  cvt_plain<<<(393216+255)/256, 256, 0, stream>>>(W_out, wpj, 393216);
  cvt_plain<<<(1572864+255)/256, 256, 0, stream>>>(W2, w2b, 1572864);
  build_oa_w<<<(589824+255)/256, 256, 0, stream>>>(W_off, W_attn, woa);
  build_oa_b<<<(2304+255)/256, 256, 0, stream>>>(b_off, b_attn, boa);
  build_w13<<<(3145728+255)/256, 256, 0, stream>>>(W1, W3, w13);
  build_b13<<<(12288+255)/256, 256, 0, stream>>>(b1, b3, bi13);

  // q init + posf
  const int HW[4]  = {16384, 4096, 1024, 256};
  const int nst[4] = {0, 16384, 20480, 21504};
  for (int l = 0; l < 4; ++l){
    dim3 g(HW[l]/64, 8, 2);
    prep_level<<<g, 256, 0, stream>>>(src[l], pos[l], le + l*256, qf, posfb, HW[l], nst[l]);
  }
  tail_writer<<<1, 64, 0, stream>>>(qf);

  for (int l = 0; l < 6; ++l){
    rmsnorm_k<<<10880, 256, 0, stream>>>(qf, g_na + l*256, posfb, nb, qinb);
    // off+attn logits -> oa48 layout
    gemm_bt<4><<<dim3(3,340), 256, 0, stream>>>(qinb, woa + (size_t)l*98304, boa + l*384, oab, nullptr, 256, 384);
    // value -> head-planes
    gemm_bt<3><<<dim3(2,340), 256, 0, stream>>>(nb, wv + (size_t)l*65536, b_val + l*256, valb, nullptr, 256, 256);
    sampler_k<<<2720, 256, 0, stream>>>(oab, valb, sampb);
    // q += ls_a * (samp @ Wp^T + bp)
    gemm_bt<2><<<dim3(2,340), 256, 0, stream>>>(sampb, wpj + (size_t)l*65536, b_out + l*256, qf, ls_a + l*256, 256, 256);
    rmsnorm_k<<<10880, 256, 0, stream>>>(qf, g_nf + l*256, nullptr, nb, nullptr);
    // h = silu(n@W1^T+b1)*(n@W3^T+b3), W1/W3 row-interleaved, logical N=2048
    gemm_bt<1><<<dim3(16,340), 256, 0, stream>>>(nb, w13 + (size_t)l*524288, bi13 + l*2048, hb, nullptr, 256, 1024);
    // q += ls_f * (h @ W2^T + b2)
    gemm_bt<2><<<dim3(2,340), 256, 0, stream>>>(hb, w2b + (size_t)l*262144, b2 + l*256, qf, ls_f + l*256, 1024, 256);
  }
  (void)in_sizes; (void)n_in; (void)out_size; (void)ws_size;
}

// Round 9
// 2217.312 us; speedup vs baseline: 1.0315x; 1.0315x over previous
//
#include <hip/hip_runtime.h>

typedef unsigned short u16;
typedef unsigned int   u32;
typedef __bf16 bf16x8 __attribute__((ext_vector_type(8)));
typedef float  f32x4  __attribute__((ext_vector_type(4)));
typedef u16    u16x4  __attribute__((ext_vector_type(4)));
typedef u32    u32x4  __attribute__((ext_vector_type(4)));

#define NTOK 21760
#define TTOK 43520   // BS * NTOK
#define DMODEL 256

__device__ __forceinline__ u16 f2bf(float f){
  u32 u = __builtin_bit_cast(u32, f);
  u32 r = u + 0x7fffu + ((u >> 16) & 1u);
  return (u16)(r >> 16);
}
__device__ __forceinline__ float bf2f(u16 h){
  u32 u = ((u32)h) << 16;
  return __builtin_bit_cast(float, u);
}
__device__ __forceinline__ float lo16(u32 u){ return __builtin_bit_cast(float, u << 16); }
__device__ __forceinline__ float hi16(u32 u){ return __builtin_bit_cast(float, u & 0xffff0000u); }

__device__ __forceinline__ void gld16(const u16* g, u16* l){
  __builtin_amdgcn_global_load_lds((const __attribute__((address_space(1))) void*)g,
                                   (__attribute__((address_space(3))) void*)l, 16, 0, 0);
}

// ---------------- weight prep ----------------
__global__ void cvt_plain(const float* __restrict__ s, u16* __restrict__ d, int n){
  int i = blockIdx.x * 256 + threadIdx.x;
  if (i < n) d[i] = f2bf(s[i]);
}
__global__ void build_oa_w(const float* __restrict__ Wo, const float* __restrict__ Wa, u16* __restrict__ dst){
  int i = blockIdx.x * 256 + threadIdx.x;
  if (i >= 6*384*256) return;
  int l = i / (384*256); int rem = i % (384*256); int r = rem >> 8; int c = rem & 255;
  float v = (r < 256) ? Wo[((size_t)l*256 + r)*256 + c] : Wa[((size_t)l*128 + (r-256))*256 + c];
  dst[i] = f2bf(v);
}
__global__ void build_oa_b(const float* __restrict__ bo, const float* __restrict__ ba, float* __restrict__ dst){
  int i = blockIdx.x * 256 + threadIdx.x;
  if (i >= 6*384) return;
  int l = i / 384; int r = i % 384;
  dst[i] = (r < 256) ? bo[l*256 + r] : ba[l*128 + (r-256)];
}
__global__ void build_w13(const float* __restrict__ W1, const float* __restrict__ W3, u16* __restrict__ dst){
  int i = blockIdx.x * 256 + threadIdx.x;
  if (i >= 6*2048*256) return;
  int l = i / (2048*256); int rem = i % (2048*256); int r = rem >> 8; int c = rem & 255;
  int f = r >> 1; int s = r & 1;
  const float* W = s ? W3 : W1;
  dst[i] = f2bf(W[((size_t)l*1024 + f)*256 + c]);
}
__global__ void build_b13(const float* __restrict__ b1, const float* __restrict__ b3, float* __restrict__ dst){
  int i = blockIdx.x * 256 + threadIdx.x;
  if (i >= 6*2048) return;
  int l = i / 2048; int r = i % 2048;
  dst[i] = (r & 1) ? b3[l*1024 + (r>>1)] : b1[l*1024 + (r>>1)];
}

// ---------------- input prep: q init (bf16) + posf (bf16) ----------------
__global__ __launch_bounds__(256)
void prep_level(const float* __restrict__ src, const float* __restrict__ pos,
                const float* __restrict__ lemb, u16* __restrict__ qb,
                u16* __restrict__ posf, int HW, int nstart){
  __shared__ float tS[32][65];
  __shared__ float tP[32][65];
  int b  = blockIdx.z;
  int d0 = blockIdx.y * 32;
  int n0 = blockIdx.x * 64;
  int tx = threadIdx.x & 63, ty = threadIdx.x >> 6;
  #pragma unroll
  for (int i = 0; i < 8; ++i){
    int d = i*4 + ty;
    size_t gi = ((size_t)b*DMODEL + d0 + d) * HW + n0 + tx;
    tS[d][tx] = src[gi];
    tP[d][tx] = pos[gi];
  }
  __syncthreads();
  int dc = threadIdx.x & 31, nl0 = threadIdx.x >> 5;
  float le = lemb[d0 + dc];
  #pragma unroll
  for (int ii = 0; ii < 8; ++ii){
    int nl = nl0 + ii*8;
    size_t oi = ((size_t)b*NTOK + nstart + n0 + nl) * DMODEL + d0 + dc;
    qb[oi]   = f2bf(tS[dc][nl]);
    posf[oi] = f2bf(tP[dc][nl] + le);
  }
}

// ---------------- finalize: qb (bf16) -> d_out fp32, + tuple tail ----------------
__global__ __launch_bounds__(256)
void finalize_k(const u16* __restrict__ qb, float* __restrict__ out){
  size_t i = (size_t)blockIdx.x * 2048 + (size_t)threadIdx.x * 8;
  u16x4 a = *(const u16x4*)(qb + i);
  u16x4 b = *(const u16x4*)(qb + i + 4);
  f32x4 fa, fb;
  #pragma unroll
  for (int r = 0; r < 4; ++r){ fa[r] = bf2f(a[r]); fb[r] = bf2f(b[r]); }
  *(f32x4*)(out + i)     = fa;
  *(f32x4*)(out + i + 4) = fb;
  if (blockIdx.x == 0 && threadIdx.x < 12){
    const float vals[12] = {128.f,128.f,64.f,64.f,32.f,32.f,16.f,16.f,
                            0.f,16384.f,20480.f,21504.f};
    out[(size_t)TTOK*DMODEL + threadIdx.x] = vals[threadIdx.x];
  }
}

// ---------------- rmsnorm on bf16 q (+ optional qin = n + posf) ----------------
__global__ __launch_bounds__(256)
void rmsnorm_k(const u16* __restrict__ q, const float* __restrict__ g,
               const u16* __restrict__ posf, u16* __restrict__ nout,
               u16* __restrict__ qinout){
  int tok  = blockIdx.x*4 + (threadIdx.x >> 6);
  int lane = threadIdx.x & 63;
  u16x4 qv4 = ((const u16x4*)(q + (size_t)tok*DMODEL))[lane];
  float v[4];
  #pragma unroll
  for (int r = 0; r < 4; ++r) v[r] = bf2f(qv4[r]);
  float ss = v[0]*v[0] + v[1]*v[1] + v[2]*v[2] + v[3]*v[3];
  #pragma unroll
  for (int o = 32; o > 0; o >>= 1) ss += __shfl_xor(ss, o);
  float sc = rsqrtf(ss * (1.0f/256.0f) + 1e-6f);
  f32x4 gv = ((const f32x4*)g)[lane];
  float nf[4]; u16x4 nv;
  #pragma unroll
  for (int r = 0; r < 4; ++r){ nf[r] = v[r]*sc*gv[r]; nv[r] = f2bf(nf[r]); }
  ((u16x4*)(nout + (size_t)tok*DMODEL))[lane] = nv;
  if (qinout){
    u16x4 pf = ((const u16x4*)(posf + (size_t)tok*DMODEL))[lane];
    u16x4 qv;
    #pragma unroll
    for (int r = 0; r < 4; ++r) qv[r] = f2bf(nf[r] + bf2f(pf[r]));
    ((u16x4*)(qinout + (size_t)tok*DMODEL))[lane] = qv;
  }
}

// ---------------- GEMM: C[m,n] = sum_k A[m,k]*B[n,k]  (A,B bf16, NT) ----------------
// XCD-swizzled (bijective, m204). 2-buffer LDS + __syncthreads (R7 structure;
// R8's 3-buffer counted-vmcnt regressed: LDS 48KB cut blocks/CU 5->3, killing
// the implicit cross-block overlap that already hid the drain).
// EPI 0: out bf16 = acc + bias          (ldo = N of this gemm)
// EPI 1: swiglu:   out bf16 h[m, col>>1] = silu(h1)*h3, cols interleaved (ldo = N/2)
// EPI 2: residual: out bf16 q += ls[col] * (acc + bias)   (ldo = N)
// EPI 3: value head-planes: out bf16 [(b*8+head)][tok][32], head=col>>5
// EPI 4: oa48 rows: out bf16 [(b*8+head)][tok][48]; col<256 -> offs[col&31],
//        col>=256 -> logits 32+(c&15), head=c>>4
template<int EPI>
__global__ __launch_bounds__(256)
void gemm_bt(const u16* __restrict__ A, const u16* __restrict__ B,
             const float* __restrict__ bias, void* __restrict__ outp,
             const float* __restrict__ ls, int K, int ldo){
  __shared__ u16 lds[2][2][4096];
  const int tid = threadIdx.x, lane = tid & 63, w = tid >> 6;
  const int wm = w >> 1, wn = w & 1;

  // bijective XCD swizzle
  const int gx = gridDim.x;
  const int nwg = gx * gridDim.y;
  const int id  = blockIdx.y * gx + blockIdx.x;
  const int q8 = nwg >> 3, r8 = nwg & 7;
  const int xcd = id & 7, pos = id >> 3;
  const int nid = (xcd < r8 ? xcd * (q8 + 1) : r8 * (q8 + 1) + (xcd - r8) * q8) + pos;
  const int bn = (nid % gx) * 128, bm = (nid / gx) * 128;

  const int fr = lane & 15, ks = lane >> 4;

  const u16* gA = A + (size_t)(bm + w*32 + (lane >> 2)) * K + (lane & 3) * 8;
  const u16* gB = B + (size_t)(bn + w*32 + (lane >> 2)) * K + (lane & 3) * 8;
  const size_t rstep = (size_t)16 * K;

  f32x4 acc[4][4];
  #pragma unroll
  for (int m = 0; m < 4; ++m)
    #pragma unroll
    for (int n = 0; n < 4; ++n) acc[m][n] = (f32x4){0.f,0.f,0.f,0.f};

  const int aoff = (wm*64 + fr)*32 + ks*8;
  const int boff = (wn*64 + fr)*32 + ks*8;

  auto STAGE = [&](int buf, int k0){
    gld16(gA + k0,         &lds[buf][0][w*1024]);
    gld16(gA + k0 + rstep, &lds[buf][0][w*1024 + 512]);
    gld16(gB + k0,         &lds[buf][1][w*1024]);
    gld16(gB + k0 + rstep, &lds[buf][1][w*1024 + 512]);
  };

  const int nk = K >> 5;
  STAGE(0, 0);
  __syncthreads();
  int buf = 0;
  for (int t = 0; t < nk; ++t){
    if (t + 1 < nk) STAGE(buf ^ 1, (t + 1) * 32);
    bf16x8 af[4], bb[4];
    #pragma unroll
    for (int m = 0; m < 4; ++m) af[m] = *(const bf16x8*)&lds[buf][0][aoff + m*512];
    #pragma unroll
    for (int n = 0; n < 4; ++n) bb[n] = *(const bf16x8*)&lds[buf][1][boff + n*512];
    #pragma unroll
    for (int m = 0; m < 4; ++m)
      #pragma unroll
      for (int n = 0; n < 4; ++n)
        acc[m][n] = __builtin_amdgcn_mfma_f32_16x16x32_bf16(af[m], bb[n], acc[m][n], 0, 0, 0);
    __syncthreads();
    buf ^= 1;
  }

  const int colb = bn + wn*64 + fr;
  const int rowb = bm + wm*64 + ks*4;

  if (EPI == 0){
    u16* o = (u16*)outp;
    #pragma unroll
    for (int n = 0; n < 4; ++n){
      int col = colb + n*16; float bv = bias[col];
      #pragma unroll
      for (int m = 0; m < 4; ++m){
        int row = rowb + m*16;
        #pragma unroll
        for (int r = 0; r < 4; ++r)
          o[(size_t)(row + r)*ldo + col] = f2bf(acc[m][n][r] + bv);
      }
    }
  } else if (EPI == 1){
    u16* o = (u16*)outp;
    #pragma unroll
    for (int n = 0; n < 4; ++n){
      int col = colb + n*16; float bv = bias[col];
      int f = col >> 1; bool even = ((col & 1) == 0);
      #pragma unroll
      for (int m = 0; m < 4; ++m){
        int row = rowb + m*16;
        #pragma unroll
        for (int r = 0; r < 4; ++r){
          float v = acc[m][n][r] + bv;
          float other = __shfl_xor(v, 1);
          if (even){
            float res = (v / (1.0f + __expf(-v))) * other;   // silu(h1)*h3
            o[(size_t)(row + r)*ldo + f] = f2bf(res);
          }
        }
      }
    }
  } else if (EPI == 2){
    u16* o = (u16*)outp;
    #pragma unroll
    for (int n = 0; n < 4; ++n){
      int col = colb + n*16; float bv = bias[col]; float lv = ls[col];
      #pragma unroll
      for (int m = 0; m < 4; ++m){
        int row = rowb + m*16;
        #pragma unroll
        for (int r = 0; r < 4; ++r){
          size_t ix = (size_t)(row + r)*ldo + col;
          o[ix] = f2bf(bf2f(o[ix]) + lv * (acc[m][n][r] + bv));
        }
      }
    }
  } else if (EPI == 3){
    // value head-planes
    u16* o = (u16*)outp;
    #pragma unroll
    for (int n = 0; n < 4; ++n){
      int col = colb + n*16; float bv = bias[col];
      int head = col >> 5, ch = col & 31;
      #pragma unroll
      for (int m = 0; m < 4; ++m){
        int row = rowb + m*16;
        #pragma unroll
        for (int r = 0; r < 4; ++r){
          int rw = row + r;
          int bb2 = rw >= NTOK ? 1 : 0;
          int tok = rw - bb2 * NTOK;
          o[((size_t)(bb2*8 + head)*NTOK + tok)*32 + ch] = f2bf(acc[m][n][r] + bv);
        }
      }
    }
  } else {
    // EPI 4: oa48 rows
    u16* o = (u16*)outp;
    #pragma unroll
    for (int n = 0; n < 4; ++n){
      int col = colb + n*16; float bv = bias[col];
      int head, within;
      if (col < 256){ head = col >> 5; within = col & 31; }
      else { int c = col - 256; head = c >> 4; within = 32 + (c & 15); }
      #pragma unroll
      for (int m = 0; m < 4; ++m){
        int row = rowb + m*16;
        #pragma unroll
        for (int r = 0; r < 4; ++r){
          int rw = row + r;
          int bb2 = rw >= NTOK ? 1 : 0;
          int tok = rw - bb2 * NTOK;
          o[((size_t)(bb2*8 + head)*NTOK + tok)*48 + within] = f2bf(acc[m][n][r] + bv);
        }
      }
    }
  }
}

// ---------------- deformable sampler ----------------
// Coalescing-first layout: wave = 32 CONSECUTIVE q (lanes 0-31 / 32-63 are the
// two level-halves of the same 32 q) for ONE (b,head). value is head-planed
// [(b*8+h)][tok][32]; oa packed [(b*8+h)][q][48]. Halves combine via
// shfl_xor(32). XCD chunking: each XCD owns 2 head-planes (~3MB, L2-fits).
__global__ __launch_bounds__(256)
void sampler_k(const u16* __restrict__ oa48, const u16* __restrict__ valpl,
               u16* __restrict__ samp){
  // 2720 blocks = 8 * 340; nid = bh*170 + qblock
  int nid = (blockIdx.x & 7) * 340 + (blockIdx.x >> 3);
  int bh = nid / 170, qb = nid % 170;
  int lane = threadIdx.x & 63, wv = threadIdx.x >> 6;
  int half = lane >> 5;
  int q = qb * 128 + wv * 32 + (lane & 31);

  int st, lw, sh;
  if (q < 16384){ st = 0;     lw = 128; sh = 7; }
  else if (q < 20480){ st = 16384; lw = 64; sh = 6; }
  else if (q < 21504){ st = 20480; lw = 32; sh = 5; }
  else { st = 21504; lw = 16; sh = 4; }
  int loc = q - st;
  int j = loc & (lw - 1), i = loc >> sh;
  float invW = 1.0f / (float)lw;
  float rx = (j + 0.5f) * invW, ry = (i + 0.5f) * invW;

  const u16* oq = oa48 + ((size_t)bh * NTOK + q) * 48;
  // softmax: each half exponentiates its own 8 logits; combine via shfl_xor(32)
  float lg[8];
  const u32* lg32 = (const u32*)(oq + 32) + half * 4;
  #pragma unroll
  for (int p = 0; p < 4; ++p){ u32 wd = lg32[p]; lg[2*p] = lo16(wd); lg[2*p+1] = hi16(wd); }
  float mx = -1e30f;
  #pragma unroll
  for (int p = 0; p < 8; ++p) mx = fmaxf(mx, lg[p]);
  mx = fmaxf(mx, __shfl_xor(mx, 32));
  float ssum = 0.f;
  #pragma unroll
  for (int p = 0; p < 8; ++p){ lg[p] = __expf(lg[p] - mx); ssum += lg[p]; }
  ssum += __shfl_xor(ssum, 32);
  float inv = 1.0f / ssum;

  float acc[32];
  #pragma unroll
  for (int d = 0; d < 32; ++d) acc[d] = 0.f;

  const u32* op32 = (const u32*)oq + half * 8;
  const u16* plane = valpl + (size_t)bh * NTOK * 32;
  #pragma unroll
  for (int il = 0; il < 2; ++il){
    const int Wl    = half ? (il ? 16 : 32)    : (il ? 64 : 128);
    const int start = half ? (il ? 21504 : 20480) : (il ? 16384 : 0);
    #pragma unroll
    for (int p = 0; p < 4; ++p){
      u32 wd = op32[il*4 + p];
      float x = rx * Wl + lo16(wd) - 0.5f;
      float y = ry * Wl + hi16(wd) - 0.5f;
      float x0f = floorf(x), y0f = floorf(y);
      int x0 = (int)x0f, y0 = (int)y0f;
      float fx = x - x0f, fy = y - y0f;
      float wp = lg[il*4 + p];
      #pragma unroll
      for (int c = 0; c < 4; ++c){
        int xi = x0 + (c & 1), yi = y0 + (c >> 1);
        float wc = ((c & 1) ? fx : 1.f - fx) * ((c >> 1) ? fy : 1.f - fy) * wp;
        if (xi >= 0 && xi < Wl && yi >= 0 && yi < Wl && wc != 0.f){
          const u32x4* vp = (const u32x4*)(plane + (size_t)(start + yi*Wl + xi) * 32);
          #pragma unroll
          for (int u4 = 0; u4 < 4; ++u4){
            u32x4 vv = vp[u4];
            #pragma unroll
            for (int jj = 0; jj < 4; ++jj){
              acc[8*u4 + 2*jj]     += wc * lo16(vv[jj]);
              acc[8*u4 + 2*jj + 1] += wc * hi16(vv[jj]);
            }
          }
        }
      }
    }
  }

  // combine halves: after this, both lanes hold the full 32-channel sum
  #pragma unroll
  for (int d = 0; d < 32; ++d) acc[d] += __shfl_xor(acc[d], 32);

  // lane writes its half's 16 channels
  u16* out = samp + ((size_t)(bh >> 3) * NTOK + q) * DMODEL + (bh & 7) * 32 + half * 16;
  #pragma unroll
  for (int d = 0; d < 16; d += 4){
    u16x4 o4;
    #pragma unroll
    for (int r = 0; r < 4; ++r) o4[r] = f2bf(acc[half*16 + d + r] * inv);
    *(u16x4*)(out + d) = o4;
  }
}

// ---------------- host ----------------
extern "C" void kernel_launch(void* const* d_in, const int* in_sizes, int n_in,
                              void* d_out, int out_size, void* d_ws, size_t ws_size,
                              hipStream_t stream){
  const float* src[4] = {(const float*)d_in[0], (const float*)d_in[2],
                         (const float*)d_in[4], (const float*)d_in[6]};
  const float* pos[4] = {(const float*)d_in[1], (const float*)d_in[3],
                         (const float*)d_in[5], (const float*)d_in[7]};
  const float* le     = (const float*)d_in[8];
  const float* W_off  = (const float*)d_in[9];  const float* b_off  = (const float*)d_in[10];
  const float* W_attn = (const float*)d_in[11]; const float* b_attn = (const float*)d_in[12];
  const float* W_val  = (const float*)d_in[13]; const float* b_val  = (const float*)d_in[14];
  const float* W_out  = (const float*)d_in[15]; const float* b_out  = (const float*)d_in[16];
  const float* g_na   = (const float*)d_in[17]; const float* g_nf   = (const float*)d_in[18];
  const float* ls_a   = (const float*)d_in[19]; const float* ls_f   = (const float*)d_in[20];
  const float* W1     = (const float*)d_in[21]; const float* b1     = (const float*)d_in[22];
  const float* W3     = (const float*)d_in[23]; const float* b3     = (const float*)d_in[24];
  const float* W2     = (const float*)d_in[25]; const float* b2     = (const float*)d_in[26];

  char* ws = (char*)d_ws;
  // ws layout (bytes)
  u16*   wv   = (u16*)  (ws + 0);          // 6*65536 bf16
  u16*   wpj  = (u16*)  (ws + 786432);     // W_out, 6*65536
  u16*   w2b  = (u16*)  (ws + 1572864);    // 6*262144
  u16*   woa  = (u16*)  (ws + 4718592);    // 6*384*256
  float* boa  = (float*)(ws + 5898240);    // 6*384
  u16*   w13  = (u16*)  (ws + 5907456);    // 6*2048*256
  float* bi13 = (float*)(ws + 12198912);   // 6*2048
  u16*   posfb= (u16*)  (ws + 12248064);   // 11141120 bf16
  u16*   nb   = (u16*)  (ws + 34530304);   // 11141120 bf16
  u16*   qinb = (u16*)  (ws + 56812544);   // 11141120 bf16
  u16*   valb = (u16*)  (ws + 79094784);   // 11141120 bf16 (head-planed)
  u16*   oab  = (u16*)  (ws + 101377024);  // 16*21760*48 bf16 (oa48)
  u16*   sampb= (u16*)  (ws + 134800384);  // 11141120 bf16
  u16*   qb   = (u16*)  (ws + 157082624);  // 11141120 bf16 residual stream
  u16*   hb   = qinb;                      // FFN h aliases qin..sampb (dead by then)
  float* qf   = (float*)d_out;

  // weight prep
  cvt_plain<<<(393216+255)/256, 256, 0, stream>>>(W_val, wv, 393216);
  cvt_plain<<<(393216+255)/256, 256, 0, stream>>>(W_out, wpj, 393216);
  cvt_plain<<<(1572864+255)/256, 256, 0, stream>>>(W2, w2b, 1572864);
  build_oa_w<<<(589824+255)/256, 256, 0, stream>>>(W_off, W_attn, woa);
  build_oa_b<<<(2304+255)/256, 256, 0, stream>>>(b_off, b_attn, boa);
  build_w13<<<(3145728+255)/256, 256, 0, stream>>>(W1, W3, w13);
  build_b13<<<(12288+255)/256, 256, 0, stream>>>(b1, b3, bi13);

  // q init + posf
  const int HW[4]  = {16384, 4096, 1024, 256};
  const int nst[4] = {0, 16384, 20480, 21504};
  for (int l = 0; l < 4; ++l){
    dim3 g(HW[l]/64, 8, 2);
    prep_level<<<g, 256, 0, stream>>>(src[l], pos[l], le + l*256, qb, posfb, HW[l], nst[l]);
  }

  for (int l = 0; l < 6; ++l){
    rmsnorm_k<<<10880, 256, 0, stream>>>(qb, g_na + l*256, posfb, nb, qinb);
    // off+attn logits -> oa48 layout
    gemm_bt<4><<<dim3(3,340), 256, 0, stream>>>(qinb, woa + (size_t)l*98304, boa + l*384, oab, nullptr, 256, 384);
    // value -> head-planes
    gemm_bt<3><<<dim3(2,340), 256, 0, stream>>>(nb, wv + (size_t)l*65536, b_val + l*256, valb, nullptr, 256, 256);
    sampler_k<<<2720, 256, 0, stream>>>(oab, valb, sampb);
    // q += ls_a * (samp @ Wp^T + bp)   (bf16 RMW)
    gemm_bt<2><<<dim3(2,340), 256, 0, stream>>>(sampb, wpj + (size_t)l*65536, b_out + l*256, qb, ls_a + l*256, 256, 256);
    rmsnorm_k<<<10880, 256, 0, stream>>>(qb, g_nf + l*256, nullptr, nb, nullptr);
    // h = silu(n@W1^T+b1)*(n@W3^T+b3), W1/W3 row-interleaved, logical N=2048
    gemm_bt<1><<<dim3(16,340), 256, 0, stream>>>(nb, w13 + (size_t)l*524288, bi13 + l*2048, hb, nullptr, 256, 1024);
    // q += ls_f * (h @ W2^T + b2)   (bf16 RMW)
    gemm_bt<2><<<dim3(2,340), 256, 0, stream>>>(hb, w2b + (size_t)l*262144, b2 + l*256, qb, ls_f + l*256, 1024, 256);
  }
  // expand bf16 residual stream to fp32 output + tuple tail
  finalize_k<<<5440, 256, 0, stream>>>(qb, qf);
  (void)in_sizes; (void)n_in; (void)out_size; (void)ws_size;
}